// Round 1
// baseline (525.508 us; speedup 1.0000x reference)
//
#include <hip/hip_runtime.h>
#include <hip/hip_bf16.h>
#include <cstdint>
#include <cstddef>

// Graph Transformer: 2x TransformerConv (H=8) + Linear(8,100) + mean over nodes.
// Round 1: all-fp32 correctness-first implementation.
//   gemm1: x[N,128] @ [Wq1|Wk1|Wv1|Ws1] -> qkvs1[N,512]   (fp32 LDS-tiled GEMM)
//   CSR build: count -> 3-stage scan -> scatter (groups edges by dst)
//   attn1: wave-per-node online softmax, lane l owns channels {2l,2l+1}
//   gemm2: h1[N,128] @ [Wq2|Wk2|Wv2|Ws2] -> qkvs2[N,32]
//   attn2: wave-per-node, 8 edges x 8 heads per iteration, two-pass softmax
//   final: relu(h2 @ Wl + bl), mean over nodes -> out[100]

#define WAVE 64

// ---------------- weight packing ----------------
__global__ __launch_bounds__(256) void pack_weights(
    const float* __restrict__ Wq1, const float* __restrict__ bq1,
    const float* __restrict__ Wk1, const float* __restrict__ bk1,
    const float* __restrict__ Wv1, const float* __restrict__ bv1,
    const float* __restrict__ Ws1, const float* __restrict__ bs1,
    const float* __restrict__ Wq2, const float* __restrict__ bq2,
    const float* __restrict__ Wk2, const float* __restrict__ bk2,
    const float* __restrict__ Wv2, const float* __restrict__ bv2,
    const float* __restrict__ Ws2, const float* __restrict__ bs2,
    float* __restrict__ Wcat1, float* __restrict__ bcat1,
    float* __restrict__ Wcat2, float* __restrict__ bcat2)
{
    int i = blockIdx.x * 256 + threadIdx.x;
    if (i < 65536) {                       // Wcat1[k][j], j: 0..511 = q|k|v|s
        int k = i >> 9, j = i & 511, sel = j >> 7, jj = j & 127;
        const float* W = sel == 0 ? Wq1 : sel == 1 ? Wk1 : sel == 2 ? Wv1 : Ws1;
        Wcat1[i] = W[k * 128 + jj];
    } else if (i < 65536 + 512) {
        int j = i - 65536, sel = j >> 7, jj = j & 127;
        const float* B = sel == 0 ? bq1 : sel == 1 ? bk1 : sel == 2 ? bv1 : bs1;
        bcat1[j] = B[jj];
    } else if (i < 65536 + 512 + 4096) {   // Wcat2[k][j], j: 0..31 = q|k|v|s
        int t = i - (65536 + 512);
        int k = t >> 5, j = t & 31, sel = j >> 3, jj = j & 7;
        const float* W = sel == 0 ? Wq2 : sel == 1 ? Wk2 : sel == 2 ? Wv2 : Ws2;
        Wcat2[t] = W[k * 8 + jj];
    } else if (i < 65536 + 512 + 4096 + 32) {
        int j = i - (65536 + 512 + 4096), sel = j >> 3, jj = j & 7;
        const float* B = sel == 0 ? bq2 : sel == 1 ? bk2 : sel == 2 ? bv2 : bs2;
        bcat2[j] = B[jj];
    }
}

// ---------------- layer-1 fused QKVS GEMM (fp32) ----------------
// 64 rows x 64 cols per block, 4x4 per thread, K=128 in 8 steps of 16.
__global__ __launch_bounds__(256) void gemm1(
    const float* __restrict__ x, const float* __restrict__ Wcat,
    const float* __restrict__ bcat, float* __restrict__ qkvs, int n)
{
    __shared__ float As[16][68];   // [k][row], pad 68 keeps 16B alignment, ~2-way banks
    __shared__ float Bs[16][68];   // [k][col]
    int tid = threadIdx.x;
    int tx = tid & 15, ty = tid >> 4;
    int rowbase = blockIdx.x * 64, colbase = blockIdx.y * 64;
    int ar = tid >> 2, ac4 = tid & 3;       // A staging: row, k-quad
    int bk = tid >> 4, bc = tid & 15;       // B staging: k, col-quad
    float acc[4][4] = {};
    for (int kt = 0; kt < 8; ++kt) {
        int kb = kt * 16;
        float4 av = make_float4(0.f, 0.f, 0.f, 0.f);
        int row = rowbase + ar;
        if (row < n) av = *(const float4*)&x[(size_t)row * 128 + kb + ac4 * 4];
        As[ac4 * 4 + 0][ar] = av.x; As[ac4 * 4 + 1][ar] = av.y;
        As[ac4 * 4 + 2][ar] = av.z; As[ac4 * 4 + 3][ar] = av.w;
        float4 bv = *(const float4*)&Wcat[(size_t)(kb + bk) * 512 + colbase + bc * 4];
        *(float4*)&Bs[bk][bc * 4] = bv;
        __syncthreads();
        #pragma unroll
        for (int k = 0; k < 16; ++k) {
            float4 a4 = *(float4*)&As[k][ty * 4];
            float4 b4 = *(float4*)&Bs[k][tx * 4];
            float af[4] = {a4.x, a4.y, a4.z, a4.w};
            float bf[4] = {b4.x, b4.y, b4.z, b4.w};
            #pragma unroll
            for (int i = 0; i < 4; ++i)
                #pragma unroll
                for (int j = 0; j < 4; ++j)
                    acc[i][j] += af[i] * bf[j];
        }
        __syncthreads();
    }
    float4 bias = *(const float4*)&bcat[colbase + tx * 4];
    float bf[4] = {bias.x, bias.y, bias.z, bias.w};
    #pragma unroll
    for (int i = 0; i < 4; ++i) {
        int row = rowbase + ty * 4 + i;
        if (row < n) {
            float4 o = make_float4(acc[i][0] + bf[0], acc[i][1] + bf[1],
                                   acc[i][2] + bf[2], acc[i][3] + bf[3]);
            *(float4*)&qkvs[(size_t)row * 512 + colbase + tx * 4] = o;
        }
    }
}

// ---------------- CSR build ----------------
__global__ __launch_bounds__(256) void count_edges(
    const int* __restrict__ ei, int* __restrict__ counts, int E)
{
    int e = blockIdx.x * 256 + threadIdx.x;
    if (e < E) atomicAdd(&counts[ei[E + e]], 1);   // dst row
}

__global__ __launch_bounds__(256) void scan1(
    const int* __restrict__ counts, int* __restrict__ indptr,
    int* __restrict__ blocksums, int n)
{
    int t = threadIdx.x, b = blockIdx.x, i = b * 256 + t;
    int v = (i < n) ? counts[i] : 0;
    int x = v;
    #pragma unroll
    for (int off = 1; off < 64; off <<= 1) {
        int y = __shfl_up(x, off, 64);
        if ((t & 63) >= off) x += y;
    }
    __shared__ int wsum[4];
    if ((t & 63) == 63) wsum[t >> 6] = x;
    __syncthreads();
    int woff = 0;
    for (int w = 0; w < (t >> 6); ++w) woff += wsum[w];
    if (i < n) indptr[i] = woff + x - v;   // block-local exclusive
    if (t == 255) blocksums[b] = woff + x;
}

__global__ __launch_bounds__(256) void scan2(
    const int* __restrict__ blocksums, int* __restrict__ blockoff,
    int* __restrict__ indptr, int nb, int n, int E)
{
    int t = threadIdx.x;
    int v = (t < nb) ? blocksums[t] : 0;
    int x = v;
    #pragma unroll
    for (int off = 1; off < 64; off <<= 1) {
        int y = __shfl_up(x, off, 64);
        if ((t & 63) >= off) x += y;
    }
    __shared__ int wsum[4];
    if ((t & 63) == 63) wsum[t >> 6] = x;
    __syncthreads();
    int woff = 0;
    for (int w = 0; w < (t >> 6); ++w) woff += wsum[w];
    if (t < nb) blockoff[t] = woff + x - v;
    if (t == 0) indptr[n] = E;
}

__global__ __launch_bounds__(256) void scan3(
    int* __restrict__ indptr, const int* __restrict__ blockoff, int n)
{
    int i = blockIdx.x * 256 + threadIdx.x;
    if (i < n) indptr[i] += blockoff[blockIdx.x];
}

__global__ __launch_bounds__(256) void scatter_edges(
    const int* __restrict__ ei, const int* __restrict__ indptr,
    int* __restrict__ fill, int* __restrict__ srcs, int E)
{
    int e = blockIdx.x * 256 + threadIdx.x;
    if (e < E) {
        int d = ei[E + e];
        int pos = indptr[d] + atomicAdd(&fill[d], 1);
        srcs[pos] = ei[e];
    }
}

// ---------------- layer-1 attention: wave per node, online softmax ----------------
// lane l: head h=l>>3, channels 2l,2l+1 of the 128-wide row (h*16 + (l&7)*2 == 2l).
__global__ __launch_bounds__(256) void attn1(
    const float* __restrict__ qkvs, const int* __restrict__ indptr,
    const int* __restrict__ srcs, float* __restrict__ h1, int n)
{
    int wid = threadIdx.x >> 6, l = threadIdx.x & 63;
    int node = blockIdx.x * 4 + wid;
    if (node >= n) return;
    int off2 = 2 * l;
    const float* qrow = qkvs + (size_t)node * 512;
    float q0 = qrow[off2], q1 = qrow[off2 + 1];
    float m = -__builtin_inff(), den = 0.f, a0 = 0.f, a1 = 0.f;
    int i0 = indptr[node], i1 = indptr[node + 1];
    for (int i = i0; i < i1; ++i) {
        int s = srcs[i];
        const float* krow = qkvs + (size_t)s * 512 + 128;
        float k0 = krow[off2], k1 = krow[off2 + 1];
        float v0 = krow[128 + off2], v1 = krow[128 + off2 + 1];
        float p = q0 * k0 + q1 * k1;
        p += __shfl_xor(p, 1, 64);
        p += __shfl_xor(p, 2, 64);
        p += __shfl_xor(p, 4, 64);         // per-head dot over 16 channels
        float alpha = p * 0.25f;           // / sqrt(16)
        float mn = fmaxf(m, alpha);
        float sc = __expf(m - mn);         // first iter: exp(-inf)=0
        float w  = __expf(alpha - mn);
        den = den * sc + w;
        a0 = a0 * sc + w * v0;
        a1 = a1 * sc + w * v1;
        m = mn;
    }
    float inv = 1.f / (den + 1e-16f);      // matches reference; empty node -> 0
    const float* srow = qkvs + (size_t)node * 512 + 384;
    h1[(size_t)node * 128 + off2]     = a0 * inv + srow[off2];
    h1[(size_t)node * 128 + off2 + 1] = a1 * inv + srow[off2 + 1];
}

// ---------------- layer-2 QKVS GEMM ----------------
__global__ __launch_bounds__(256) void gemm2(
    const float* __restrict__ h1, const float* __restrict__ W,
    const float* __restrict__ b, float* __restrict__ qkvs2, int n)
{
    int tid = threadIdx.x;
    int node = blockIdx.x * 8 + (tid >> 5), j = tid & 31;
    if (node >= n) return;
    const float* xr = h1 + (size_t)node * 128;
    float acc = b[j];
    #pragma unroll 8
    for (int k = 0; k < 128; ++k) acc += xr[k] * W[k * 32 + j];
    qkvs2[(size_t)node * 32 + j] = acc;
}

// ---------------- layer-2 attention: wave per node, 8 edges x 8 heads ----------------
__global__ __launch_bounds__(256) void attn2(
    const float* __restrict__ qkvs2, const int* __restrict__ indptr,
    const int* __restrict__ srcs, float* __restrict__ h2, int n)
{
    int wid = threadIdx.x >> 6, l = threadIdx.x & 63;
    int node = blockIdx.x * 4 + wid;
    if (node >= n) return;
    int i = l >> 3, h = l & 7;             // edge slot, head
    const float* base = qkvs2 + (size_t)node * 32;
    float qh = base[h];
    int i0 = indptr[node], i1 = indptr[node + 1];
    float mv = -__builtin_inff();
    for (int p = i0 + i; p < i1; p += 8) {
        int s = srcs[p];
        mv = fmaxf(mv, qh * qkvs2[(size_t)s * 32 + 8 + h]);
    }
    mv = fmaxf(mv, __shfl_xor(mv, 8, 64));
    mv = fmaxf(mv, __shfl_xor(mv, 16, 64));
    mv = fmaxf(mv, __shfl_xor(mv, 32, 64));
    float den = 0.f, acc = 0.f;
    for (int p = i0 + i; p < i1; p += 8) {
        int s = srcs[p];
        float w = __expf(qh * qkvs2[(size_t)s * 32 + 8 + h] - mv);
        den += w;
        acc += w * qkvs2[(size_t)s * 32 + 16 + h];
    }
    den += __shfl_xor(den, 8, 64); den += __shfl_xor(den, 16, 64); den += __shfl_xor(den, 32, 64);
    acc += __shfl_xor(acc, 8, 64); acc += __shfl_xor(acc, 16, 64); acc += __shfl_xor(acc, 32, 64);
    if (i == 0)
        h2[(size_t)node * 8 + h] = acc / (den + 1e-16f) + base[24 + h];
}

// ---------------- final head: relu(h2 @ Wl + bl), mean over nodes ----------------
__global__ __launch_bounds__(128) void final_reduce(
    const float* __restrict__ h2, const float* __restrict__ Wl,
    const float* __restrict__ bl, float* __restrict__ out, int n, int chunk)
{
    int j = threadIdx.x;
    bool act = j < 100;
    float wl[8] = {};
    float bj = 0.f;
    if (act) {
        #pragma unroll
        for (int t = 0; t < 8; ++t) wl[t] = Wl[t * 100 + j];
        bj = bl[j];
    }
    int lo = blockIdx.x * chunk, hi = min(n, lo + chunk);
    float acc = 0.f;
    for (int node = lo; node < hi; ++node) {
        const float* hr = h2 + (size_t)node * 8;
        float y = bj;
        #pragma unroll
        for (int t = 0; t < 8; ++t) y += hr[t] * wl[t];
        acc += fmaxf(y, 0.f);
    }
    if (act) atomicAdd(&out[j], acc * (1.f / (float)n));
}

// ---------------- launch ----------------
extern "C" void kernel_launch(void* const* d_in, const int* in_sizes, int n_in,
                              void* d_out, int out_size, void* d_ws, size_t ws_size,
                              hipStream_t stream)
{
    const float* x   = (const float*)d_in[0];
    const int*   ei  = (const int*)d_in[1];
    const float* Wq1 = (const float*)d_in[2],  *bq1 = (const float*)d_in[3];
    const float* Wk1 = (const float*)d_in[4],  *bk1 = (const float*)d_in[5];
    const float* Wv1 = (const float*)d_in[6],  *bv1 = (const float*)d_in[7];
    const float* Ws1 = (const float*)d_in[8],  *bs1 = (const float*)d_in[9];
    const float* Wq2 = (const float*)d_in[10], *bq2 = (const float*)d_in[11];
    const float* Wk2 = (const float*)d_in[12], *bk2 = (const float*)d_in[13];
    const float* Wv2 = (const float*)d_in[14], *bv2 = (const float*)d_in[15];
    const float* Ws2 = (const float*)d_in[16], *bs2 = (const float*)d_in[17];
    const float* Wl  = (const float*)d_in[18], *bl  = (const float*)d_in[19];
    float* out = (float*)d_out;

    int n = in_sizes[0] / 128;     // 50000
    int E = in_sizes[1] / 2;       // 800000

    // workspace carve (256B aligned)
    char* p = (char*)d_ws;
    auto take = [&](size_t bytes) -> void* {
        void* r = (void*)p;
        p += (bytes + 255) & ~(size_t)255;
        return r;
    };
    float* qkvs1  = (float*)take((size_t)n * 512 * 4);   // 102.4 MB
    float* h1     = (float*)take((size_t)n * 128 * 4);   // 25.6 MB
    float* qkvs2  = (float*)take((size_t)n * 32 * 4);    // 6.4 MB
    float* h2     = (float*)take((size_t)n * 8 * 4);     // 1.6 MB
    float* Wcat1  = (float*)take(65536 * 4);
    float* bcat1  = (float*)take(512 * 4);
    float* Wcat2  = (float*)take(4096 * 4);
    float* bcat2  = (float*)take(32 * 4);
    int*   counts = (int*)take((size_t)n * 4);
    int*   fill   = (int*)take((size_t)n * 4);
    int*   indptr = (int*)take((size_t)(n + 1) * 4);
    int*   srcs   = (int*)take((size_t)E * 4);
    int    nb     = (n + 255) / 256;                     // 196 scan blocks
    int*   blocksums = (int*)take((size_t)nb * 4);
    int*   blockoff  = (int*)take((size_t)nb * 4);

    hipMemsetAsync(counts, 0, (size_t)n * 4, stream);
    hipMemsetAsync(fill, 0, (size_t)n * 4, stream);
    hipMemsetAsync(out, 0, (size_t)out_size * 4, stream);

    pack_weights<<<(70176 + 255) / 256, 256, 0, stream>>>(
        Wq1, bq1, Wk1, bk1, Wv1, bv1, Ws1, bs1,
        Wq2, bq2, Wk2, bk2, Wv2, bv2, Ws2, bs2,
        Wcat1, bcat1, Wcat2, bcat2);

    gemm1<<<dim3((n + 63) / 64, 8), 256, 0, stream>>>(x, Wcat1, bcat1, qkvs1, n);

    count_edges<<<(E + 255) / 256, 256, 0, stream>>>(ei, counts, E);
    scan1<<<nb, 256, 0, stream>>>(counts, indptr, blocksums, n);
    scan2<<<1, 256, 0, stream>>>(blocksums, blockoff, indptr, nb, n, E);
    scan3<<<nb, 256, 0, stream>>>(indptr, blockoff, n);
    scatter_edges<<<(E + 255) / 256, 256, 0, stream>>>(ei, indptr, fill, srcs, E);

    attn1<<<(n + 3) / 4, 256, 0, stream>>>(qkvs1, indptr, srcs, h1, n);
    gemm2<<<(n + 7) / 8, 256, 0, stream>>>(h1, Wcat2, bcat2, qkvs2, n);
    attn2<<<(n + 3) / 4, 256, 0, stream>>>(qkvs2, indptr, srcs, h2, n);

    int chunk = (n + 255) / 256;
    final_reduce<<<256, 128, 0, stream>>>(h2, Wl, bl, out, n, chunk);
}

// Round 2
// 363.810 us; speedup vs baseline: 1.4445x; 1.4445x over previous
//
#include <hip/hip_runtime.h>
#include <hip/hip_bf16.h>
#include <cstdint>
#include <cstddef>

// Graph Transformer: 2x TransformerConv (H=8) + Linear(8,100) + mean over nodes.
// Round 2: fp16 intermediates + f16 MFMA GEMMs.
//   to_half : x fp32 -> fp16
//   pack    : weights -> fp16 TRANSPOSED [out][in] (q|k|v|s concatenated)
//   gemm1   : MFMA 64x64 tile, K=128, fp32 accum, fp16 out via LDS-coalesced epilogue
//   CSR     : count -> scan -> scatter (unchanged)
//   attn1   : wave/node online softmax, fp16 gathers (256B/row, halved traffic)
//   gemm2   : MFMA 64x32, fp16 out
//   attn2   : wave/node, 8 edges x 8 heads, fp16 gathers
//   final   : relu(h2 @ Wl + bl), mean -> out[100]

typedef _Float16 half8  __attribute__((ext_vector_type(8)));
typedef _Float16 half2_t __attribute__((ext_vector_type(2)));
typedef float    f32x4  __attribute__((ext_vector_type(4)));

// ---------------- fp32 -> fp16 convert (x) ----------------
__global__ __launch_bounds__(256) void to_half(
    const float* __restrict__ x, _Float16* __restrict__ xh, int total8)
{
    int i = blockIdx.x * 256 + threadIdx.x;
    if (i >= total8) return;
    float4 f0 = ((const float4*)x)[2 * i];
    float4 f1 = ((const float4*)x)[2 * i + 1];
    half8 h = { (_Float16)f0.x, (_Float16)f0.y, (_Float16)f0.z, (_Float16)f0.w,
                (_Float16)f1.x, (_Float16)f1.y, (_Float16)f1.z, (_Float16)f1.w };
    ((half8*)xh)[i] = h;
}

// ---------------- weight packing: fp16, transposed [out][in] ----------------
__global__ __launch_bounds__(256) void pack_weights(
    const float* __restrict__ Wq1, const float* __restrict__ bq1,
    const float* __restrict__ Wk1, const float* __restrict__ bk1,
    const float* __restrict__ Wv1, const float* __restrict__ bv1,
    const float* __restrict__ Ws1, const float* __restrict__ bs1,
    const float* __restrict__ Wq2, const float* __restrict__ bq2,
    const float* __restrict__ Wk2, const float* __restrict__ bk2,
    const float* __restrict__ Wv2, const float* __restrict__ bv2,
    const float* __restrict__ Ws2, const float* __restrict__ bs2,
    _Float16* __restrict__ Wt1, float* __restrict__ b1,
    _Float16* __restrict__ Wt2, float* __restrict__ b2)
{
    int i = blockIdx.x * 256 + threadIdx.x;
    if (i < 65536) {                       // Wt1[j][k] = W[k][jj], j = q|k|v|s col
        int j = i >> 7, k = i & 127, sel = j >> 7, jj = j & 127;
        const float* W = sel == 0 ? Wq1 : sel == 1 ? Wk1 : sel == 2 ? Wv1 : Ws1;
        Wt1[i] = (_Float16)W[k * 128 + jj];
    } else if (i < 66048) {
        int j = i - 65536, sel = j >> 7, jj = j & 127;
        const float* B = sel == 0 ? bq1 : sel == 1 ? bk1 : sel == 2 ? bv1 : bs1;
        b1[j] = B[jj];
    } else if (i < 66048 + 4096) {         // Wt2[j][k]
        int t = i - 66048;
        int j = t >> 7, k = t & 127, sel = j >> 3, jj = j & 7;
        const float* W = sel == 0 ? Wq2 : sel == 1 ? Wk2 : sel == 2 ? Wv2 : Ws2;
        Wt2[t] = (_Float16)W[k * 8 + jj];
    } else if (i < 66048 + 4096 + 32) {
        int j = i - (66048 + 4096), sel = j >> 3, jj = j & 7;
        const float* B = sel == 0 ? bq2 : sel == 1 ? bk2 : sel == 2 ? bv2 : bs2;
        b2[j] = B[jj];
    }
}

// ---------------- gemm1: qkvs1[N,512] = xh[N,128] @ Wt1^T, f16 MFMA ----------------
// 64x64 block tile, 4 waves in 2x2, each wave 32x32 (2x2 frags), K=128 in 4 steps.
__global__ __launch_bounds__(256) void gemm1(
    const _Float16* __restrict__ xh, const _Float16* __restrict__ Wt1,
    const float* __restrict__ b1, _Float16* __restrict__ qkvs, int n)
{
    __shared__ _Float16 As[64][136];   // [row][k], pad 8 halves: 272B stride, 16B aligned
    __shared__ _Float16 Bs[64][136];   // [col][k] (Wt1 is already [out][in])
    __shared__ _Float16 Ds[64][72];    // epilogue staging for coalesced fp16 writes
    int tid = threadIdx.x;
    int rowbase = blockIdx.x * 64, colbase = blockIdx.y * 64;
    #pragma unroll
    for (int it = 0; it < 4; ++it) {   // A: 64 rows x 16 chunks(16B)
        int c = it * 256 + tid, row = c >> 4, ch = c & 15;
        half8 v = {};
        if (rowbase + row < n) v = *(const half8*)&xh[(size_t)(rowbase + row) * 128 + ch * 8];
        *(half8*)&As[row][ch * 8] = v;
    }
    #pragma unroll
    for (int it = 0; it < 4; ++it) {   // B: 64 cols x 16 chunks
        int c = it * 256 + tid, row = c >> 4, ch = c & 15;
        *(half8*)&Bs[row][ch * 8] = *(const half8*)&Wt1[(size_t)(colbase + row) * 128 + ch * 8];
    }
    __syncthreads();
    int w = tid >> 6, l = tid & 63;
    int wm = w >> 1, wn = w & 1, fr = l & 15, fg = l >> 4;
    f32x4 acc[2][2] = {};
    #pragma unroll
    for (int kk = 0; kk < 4; ++kk) {
        int ko = kk * 32 + fg * 8;
        half8 a0 = *(const half8*)&As[wm * 32 + fr][ko];
        half8 a1 = *(const half8*)&As[wm * 32 + 16 + fr][ko];
        half8 b0 = *(const half8*)&Bs[wn * 32 + fr][ko];
        half8 b1v = *(const half8*)&Bs[wn * 32 + 16 + fr][ko];
        acc[0][0] = __builtin_amdgcn_mfma_f32_16x16x32_f16(a0, b0, acc[0][0], 0, 0, 0);
        acc[0][1] = __builtin_amdgcn_mfma_f32_16x16x32_f16(a0, b1v, acc[0][1], 0, 0, 0);
        acc[1][0] = __builtin_amdgcn_mfma_f32_16x16x32_f16(a1, b0, acc[1][0], 0, 0, 0);
        acc[1][1] = __builtin_amdgcn_mfma_f32_16x16x32_f16(a1, b1v, acc[1][1], 0, 0, 0);
    }
    #pragma unroll
    for (int nt = 0; nt < 2; ++nt) {   // C/D layout (m89): col=lane&15, row=(lane>>4)*4+r
        int col = wn * 32 + nt * 16 + fr;
        float bv = b1[colbase + col];
        #pragma unroll
        for (int mt = 0; mt < 2; ++mt)
            #pragma unroll
            for (int r = 0; r < 4; ++r)
                Ds[wm * 32 + mt * 16 + fg * 4 + r][col] = (_Float16)(acc[mt][nt][r] + bv);
    }
    __syncthreads();
    #pragma unroll
    for (int it = 0; it < 2; ++it) {   // coalesced out: 64 rows x 8 chunks(16B)
        int c = it * 256 + tid, row = c >> 3, ch = c & 7;
        if (rowbase + row < n)
            *(half8*)&qkvs[(size_t)(rowbase + row) * 512 + colbase + ch * 8] =
                *(const half8*)&Ds[row][ch * 8];
    }
}

// ---------------- CSR build ----------------
__global__ __launch_bounds__(256) void count_edges(
    const int* __restrict__ ei, int* __restrict__ counts, int E)
{
    int e = blockIdx.x * 256 + threadIdx.x;
    if (e < E) atomicAdd(&counts[ei[E + e]], 1);
}

__global__ __launch_bounds__(256) void scan1(
    const int* __restrict__ counts, int* __restrict__ indptr,
    int* __restrict__ blocksums, int n)
{
    int t = threadIdx.x, b = blockIdx.x, i = b * 256 + t;
    int v = (i < n) ? counts[i] : 0;
    int x = v;
    #pragma unroll
    for (int off = 1; off < 64; off <<= 1) {
        int y = __shfl_up(x, off, 64);
        if ((t & 63) >= off) x += y;
    }
    __shared__ int wsum[4];
    if ((t & 63) == 63) wsum[t >> 6] = x;
    __syncthreads();
    int woff = 0;
    for (int w = 0; w < (t >> 6); ++w) woff += wsum[w];
    if (i < n) indptr[i] = woff + x - v;
    if (t == 255) blocksums[b] = woff + x;
}

__global__ __launch_bounds__(256) void scan2(
    const int* __restrict__ blocksums, int* __restrict__ blockoff,
    int* __restrict__ indptr, int nb, int n, int E)
{
    int t = threadIdx.x;
    int v = (t < nb) ? blocksums[t] : 0;
    int x = v;
    #pragma unroll
    for (int off = 1; off < 64; off <<= 1) {
        int y = __shfl_up(x, off, 64);
        if ((t & 63) >= off) x += y;
    }
    __shared__ int wsum[4];
    if ((t & 63) == 63) wsum[t >> 6] = x;
    __syncthreads();
    int woff = 0;
    for (int w = 0; w < (t >> 6); ++w) woff += wsum[w];
    if (t < nb) blockoff[t] = woff + x - v;
    if (t == 0) indptr[n] = E;
}

__global__ __launch_bounds__(256) void scan3(
    int* __restrict__ indptr, const int* __restrict__ blockoff, int n)
{
    int i = blockIdx.x * 256 + threadIdx.x;
    if (i < n) indptr[i] += blockoff[blockIdx.x];
}

__global__ __launch_bounds__(256) void scatter_edges(
    const int* __restrict__ ei, const int* __restrict__ indptr,
    int* __restrict__ fill, int* __restrict__ srcs, int E)
{
    int e = blockIdx.x * 256 + threadIdx.x;
    if (e < E) {
        int d = ei[E + e];
        int pos = indptr[d] + atomicAdd(&fill[d], 1);
        srcs[pos] = ei[e];
    }
}

// ---------------- attn1: wave/node online softmax, fp16 gathers ----------------
__global__ __launch_bounds__(256) void attn1(
    const _Float16* __restrict__ qkvs, const int* __restrict__ indptr,
    const int* __restrict__ srcs, _Float16* __restrict__ h1, int n)
{
    int wid = threadIdx.x >> 6, l = threadIdx.x & 63;
    int node = blockIdx.x * 4 + wid;
    if (node >= n) return;
    const _Float16* nrow = qkvs + (size_t)node * 512;
    half2_t q = ((const half2_t*)nrow)[l];
    float q0 = (float)q.x, q1 = (float)q.y;
    float m = -__builtin_inff(), den = 0.f, a0 = 0.f, a1 = 0.f;
    auto upd = [&](float k0, float k1, float v0, float v1) {
        float p = q0 * k0 + q1 * k1;
        p += __shfl_xor(p, 1, 64);
        p += __shfl_xor(p, 2, 64);
        p += __shfl_xor(p, 4, 64);         // dot over the head's 16 channels
        float alpha = p * 0.25f;           // / sqrt(16)
        float mn = fmaxf(m, alpha);
        float sc = __expf(m - mn), wgt = __expf(alpha - mn);
        den = den * sc + wgt;
        a0 = a0 * sc + wgt * v0;
        a1 = a1 * sc + wgt * v1;
        m = mn;
    };
    int i0 = indptr[node], i1 = indptr[node + 1];
    int i = i0;
    for (; i + 2 <= i1; i += 2) {          // unroll-2: overlap the two gathers
        int s0 = srcs[i], s1 = srcs[i + 1];
        const _Float16* r0 = qkvs + (size_t)s0 * 512;
        const _Float16* r1 = qkvs + (size_t)s1 * 512;
        half2_t ka = ((const half2_t*)(r0 + 128))[l];
        half2_t va = ((const half2_t*)(r0 + 256))[l];
        half2_t kb = ((const half2_t*)(r1 + 128))[l];
        half2_t vb = ((const half2_t*)(r1 + 256))[l];
        upd((float)ka.x, (float)ka.y, (float)va.x, (float)va.y);
        upd((float)kb.x, (float)kb.y, (float)vb.x, (float)vb.y);
    }
    if (i < i1) {
        const _Float16* r0 = qkvs + (size_t)srcs[i] * 512;
        half2_t ka = ((const half2_t*)(r0 + 128))[l];
        half2_t va = ((const half2_t*)(r0 + 256))[l];
        upd((float)ka.x, (float)ka.y, (float)va.x, (float)va.y);
    }
    float inv = 1.f / (den + 1e-16f);
    half2_t s2 = ((const half2_t*)(nrow + 384))[l];
    half2_t o;
    o.x = (_Float16)(a0 * inv + (float)s2.x);
    o.y = (_Float16)(a1 * inv + (float)s2.y);
    ((half2_t*)(h1 + (size_t)node * 128))[l] = o;
}

// ---------------- gemm2: qkvs2[N,32] = h1[N,128] @ Wt2^T, f16 MFMA ----------------
__global__ __launch_bounds__(256) void gemm2(
    const _Float16* __restrict__ h1, const _Float16* __restrict__ Wt2,
    const float* __restrict__ b2, _Float16* __restrict__ qkvs2, int n)
{
    __shared__ _Float16 As[64][136];
    __shared__ _Float16 Bs[32][136];
    int tid = threadIdx.x;
    int rowbase = blockIdx.x * 64;
    #pragma unroll
    for (int it = 0; it < 4; ++it) {
        int c = it * 256 + tid, row = c >> 4, ch = c & 15;
        half8 v = {};
        if (rowbase + row < n) v = *(const half8*)&h1[(size_t)(rowbase + row) * 128 + ch * 8];
        *(half8*)&As[row][ch * 8] = v;
    }
    #pragma unroll
    for (int it = 0; it < 2; ++it) {
        int c = it * 256 + tid, row = c >> 4, ch = c & 15;
        *(half8*)&Bs[row][ch * 8] = *(const half8*)&Wt2[row * 128 + ch * 8];
    }
    __syncthreads();
    int w = tid >> 6, l = tid & 63, fr = l & 15, fg = l >> 4;
    f32x4 acc[2] = {};
    #pragma unroll
    for (int kk = 0; kk < 4; ++kk) {
        int ko = kk * 32 + fg * 8;
        half8 a = *(const half8*)&As[w * 16 + fr][ko];
        half8 b0 = *(const half8*)&Bs[fr][ko];
        half8 b1v = *(const half8*)&Bs[16 + fr][ko];
        acc[0] = __builtin_amdgcn_mfma_f32_16x16x32_f16(a, b0, acc[0], 0, 0, 0);
        acc[1] = __builtin_amdgcn_mfma_f32_16x16x32_f16(a, b1v, acc[1], 0, 0, 0);
    }
    #pragma unroll
    for (int nt = 0; nt < 2; ++nt) {
        int col = nt * 16 + fr;
        float bv = b2[col];
        #pragma unroll
        for (int r = 0; r < 4; ++r) {
            int row = rowbase + w * 16 + fg * 4 + r;
            if (row < n) qkvs2[(size_t)row * 32 + col] = (_Float16)(acc[nt][r] + bv);
        }
    }
}

// ---------------- attn2: wave/node, 8 edge slots x 8 heads ----------------
__global__ __launch_bounds__(256) void attn2(
    const _Float16* __restrict__ q2, const int* __restrict__ indptr,
    const int* __restrict__ srcs, float* __restrict__ h2, int n)
{
    int wid = threadIdx.x >> 6, l = threadIdx.x & 63;
    int node = blockIdx.x * 4 + wid;
    if (node >= n) return;
    int i = l >> 3, h = l & 7;
    const _Float16* base = q2 + (size_t)node * 32;
    float qh = (float)base[h];
    int i0 = indptr[node], i1 = indptr[node + 1];
    float mv = -__builtin_inff();
    for (int p = i0 + i; p < i1; p += 8)
        mv = fmaxf(mv, qh * (float)q2[(size_t)srcs[p] * 32 + 8 + h]);
    mv = fmaxf(mv, __shfl_xor(mv, 8, 64));
    mv = fmaxf(mv, __shfl_xor(mv, 16, 64));
    mv = fmaxf(mv, __shfl_xor(mv, 32, 64));
    float den = 0.f, acc = 0.f;
    for (int p = i0 + i; p < i1; p += 8) {
        int s = srcs[p];
        float wgt = __expf(qh * (float)q2[(size_t)s * 32 + 8 + h] - mv);
        den += wgt;
        acc += wgt * (float)q2[(size_t)s * 32 + 16 + h];
    }
    den += __shfl_xor(den, 8, 64); den += __shfl_xor(den, 16, 64); den += __shfl_xor(den, 32, 64);
    acc += __shfl_xor(acc, 8, 64); acc += __shfl_xor(acc, 16, 64); acc += __shfl_xor(acc, 32, 64);
    if (i == 0)
        h2[(size_t)node * 8 + h] = acc / (den + 1e-16f) + (float)base[24 + h];
}

// ---------------- final head ----------------
__global__ __launch_bounds__(128) void final_reduce(
    const float* __restrict__ h2, const float* __restrict__ Wl,
    const float* __restrict__ bl, float* __restrict__ out, int n, int chunk)
{
    int j = threadIdx.x;
    bool act = j < 100;
    float wl[8] = {};
    float bj = 0.f;
    if (act) {
        #pragma unroll
        for (int t = 0; t < 8; ++t) wl[t] = Wl[t * 100 + j];
        bj = bl[j];
    }
    int lo = blockIdx.x * chunk, hi = min(n, lo + chunk);
    float acc = 0.f;
    for (int node = lo; node < hi; ++node) {
        const float* hr = h2 + (size_t)node * 8;
        float y = bj;
        #pragma unroll
        for (int t = 0; t < 8; ++t) y += hr[t] * wl[t];
        acc += fmaxf(y, 0.f);
    }
    if (act) atomicAdd(&out[j], acc * (1.f / (float)n));
}

// ---------------- launch ----------------
extern "C" void kernel_launch(void* const* d_in, const int* in_sizes, int n_in,
                              void* d_out, int out_size, void* d_ws, size_t ws_size,
                              hipStream_t stream)
{
    const float* x   = (const float*)d_in[0];
    const int*   ei  = (const int*)d_in[1];
    const float* Wq1 = (const float*)d_in[2],  *bq1 = (const float*)d_in[3];
    const float* Wk1 = (const float*)d_in[4],  *bk1 = (const float*)d_in[5];
    const float* Wv1 = (const float*)d_in[6],  *bv1 = (const float*)d_in[7];
    const float* Ws1 = (const float*)d_in[8],  *bs1 = (const float*)d_in[9];
    const float* Wq2 = (const float*)d_in[10], *bq2 = (const float*)d_in[11];
    const float* Wk2 = (const float*)d_in[12], *bk2 = (const float*)d_in[13];
    const float* Wv2 = (const float*)d_in[14], *bv2 = (const float*)d_in[15];
    const float* Ws2 = (const float*)d_in[16], *bs2 = (const float*)d_in[17];
    const float* Wl  = (const float*)d_in[18], *bl  = (const float*)d_in[19];
    float* out = (float*)d_out;

    int n = in_sizes[0] / 128;     // 50000
    int E = in_sizes[1] / 2;       // 800000

    char* p = (char*)d_ws;
    auto take = [&](size_t bytes) -> void* {
        void* r = (void*)p;
        p += (bytes + 255) & ~(size_t)255;
        return r;
    };
    _Float16* xh     = (_Float16*)take((size_t)n * 128 * 2);
    _Float16* qkvs1  = (_Float16*)take((size_t)n * 512 * 2);
    _Float16* h1     = (_Float16*)take((size_t)n * 128 * 2);
    _Float16* qkvs2  = (_Float16*)take((size_t)n * 32 * 2);
    float*    h2     = (float*)take((size_t)n * 8 * 4);
    _Float16* Wt1    = (_Float16*)take(65536 * 2);
    float*    b1     = (float*)take(512 * 4);
    _Float16* Wt2    = (_Float16*)take(4096 * 2);
    float*    b2     = (float*)take(32 * 4);
    int*      counts = (int*)take((size_t)n * 4);
    int*      fill   = (int*)take((size_t)n * 4);
    int*      indptr = (int*)take((size_t)(n + 1) * 4);
    int*      srcs   = (int*)take((size_t)E * 4);
    int       nb     = (n + 255) / 256;
    int*      blocksums = (int*)take((size_t)nb * 4);
    int*      blockoff  = (int*)take((size_t)nb * 4);

    hipMemsetAsync(counts, 0, (size_t)n * 4, stream);
    hipMemsetAsync(fill, 0, (size_t)n * 4, stream);
    hipMemsetAsync(out, 0, (size_t)out_size * 4, stream);

    to_half<<<(n * 128 / 8 + 255) / 256, 256, 0, stream>>>(x, xh, n * 128 / 8);
    pack_weights<<<(70176 + 255) / 256, 256, 0, stream>>>(
        Wq1, bq1, Wk1, bk1, Wv1, bv1, Ws1, bs1,
        Wq2, bq2, Wk2, bk2, Wv2, bv2, Ws2, bs2,
        Wt1, b1, Wt2, b2);

    count_edges<<<(E + 255) / 256, 256, 0, stream>>>(ei, counts, E);
    scan1<<<nb, 256, 0, stream>>>(counts, indptr, blocksums, n);
    scan2<<<1, 256, 0, stream>>>(blocksums, blockoff, indptr, nb, n, E);
    scan3<<<nb, 256, 0, stream>>>(indptr, blockoff, n);
    scatter_edges<<<(E + 255) / 256, 256, 0, stream>>>(ei, indptr, fill, srcs, E);

    gemm1<<<dim3((n + 63) / 64, 8), 256, 0, stream>>>(xh, Wt1, b1, qkvs1, n);
    attn1<<<(n + 3) / 4, 256, 0, stream>>>(qkvs1, indptr, srcs, h1, n);
    gemm2<<<(n + 63) / 64, 256, 0, stream>>>(h1, Wt2, b2, qkvs2, n);
    attn2<<<(n + 3) / 4, 256, 0, stream>>>(qkvs2, indptr, srcs, h2, n);

    int chunk = (n + 255) / 256;
    final_reduce<<<256, 128, 0, stream>>>(h2, Wl, bl, out, n, chunk);
}